// Round 3
// baseline (13527.893 us; speedup 1.0000x reference)
//
#include <hip/hip_runtime.h>

#define B_   64
#define T_   512
#define D_   512
#define H_   1024
#define G4   4096      // 4*H
#define KTOT 1536      // D + H
#define KC_N 48        // KTOT / 32
#define AP   1544      // padded LDS A-row stride (1536 + 8): breaks 32-bank aliasing

typedef float f32x4 __attribute__((ext_vector_type(4)));
typedef short s16x8 __attribute__((ext_vector_type(8)));

__device__ __forceinline__ unsigned short f2bf(float f) {
    unsigned int u = __float_as_uint(f);
    u = (u + 0x7fffu + ((u >> 16) & 1u)) >> 16;   // RNE
    return (unsigned short)u;
}
__device__ __forceinline__ float bf2f(unsigned short h) {
    return __uint_as_float(((unsigned int)h) << 16);
}
__device__ __forceinline__ float sigm(float x) { return 1.f / (1.f + __expf(-x)); }
__device__ __forceinline__ float tanh_f(float x) { return 1.f - 2.f / (__expf(2.f * x) + 1.f); }

// Pack [W_ih | W_hh] into exact MFMA B-fragment order, bf16, gate-interleaved
// packed col n = 4*j_hidden + gate. Wpk[(((c*48 + kc)*64 + lane))*8 + j] =
// W[row(n)][k], n = c*16 + (lane&15), k = kc*32 + (lane>>4)*8 + j.
__global__ __launch_bounds__(256) void pack_w(const float* __restrict__ W_ih,
                                              const float* __restrict__ W_hh,
                                              unsigned short* __restrict__ Wpk) {
    int tid = blockIdx.x * 256 + threadIdx.x;        // [0, 256*48*64*8)
    int j    = tid & 7;
    int lane = (tid >> 3) & 63;
    int rest = tid >> 9;
    int kc = rest % KC_N;
    int c  = rest / KC_N;
    int npk = c * 16 + (lane & 15);
    int jh = npk >> 2, g = npk & 3;
    int row = g * H_ + jh;                           // torch gate order i,f,g,o
    int k = kc * 32 + (lane >> 4) * 8 + j;
    float v = (k < D_) ? W_ih[row * D_ + k] : W_hh[row * H_ + (k - D_)];
    Wpk[tid] = f2bf(v);
}

__global__ __launch_bounds__(256) void init_state(const float* __restrict__ h0,
                                                  const float* __restrict__ b_ih,
                                                  const float* __restrict__ b_hh,
                                                  unsigned short* __restrict__ h_a,
                                                  float* __restrict__ bias_p,
                                                  int* __restrict__ bar) {
    int tid = blockIdx.x * 256 + threadIdx.x;        // 65536
    int j = tid & (H_ - 1);
    h_a[tid] = f2bf(h0[j]);
    if (tid < G4) {                                  // bias in packed-col order
        int jh = tid >> 2, g = tid & 3;
        bias_p[tid] = b_ih[g * H_ + jh] + b_hh[g * H_ + jh];
    }
    if (tid < 4 * 64 * 16) bar[tid] = 0;             // barrier slots (padded)
}

// Persistent recurrence: 256 blocks = 4 batch groups x 64 col blocks, all 512
// timesteps in one plain launch (grid == #CUs -> co-resident at 1 block/CU).
// Weights live in VGPRs (48 s16x8 frags/lane). bg = blk&3 confines each
// group's 64 blocks to 2 XCDs under round-robin dispatch (L2/flag locality).
__global__ __launch_bounds__(256, 1) void lstm_persist(
    const float* __restrict__ x, const int* __restrict__ mask,
    const unsigned short* __restrict__ Wpk, const float* __restrict__ bias_p,
    const float* __restrict__ c0,
    unsigned short* __restrict__ h_a, unsigned short* __restrict__ h_b,
    float* __restrict__ out, int* __restrict__ bar)
{
    __shared__ unsigned short At[16 * AP];   // [x_t | h] tile, bf16, padded rows
    __shared__ float Dl[16][66];             // gates f32, padded

    const int tid = threadIdx.x;
    const int blk = blockIdx.x;
    const int bg  = blk & 3;                 // batch group 0..3 (XCD-confined)
    const int bxc = blk >> 2;                // col block 0..63
    const int b0  = bg * 16;
    const int w = tid >> 6, l = tid & 63;
    const int quad = l >> 4, l15 = l & 15;
    const int cgrp = bxc * 4 + w;            // global 16-col group [0,256)

    // ---- load this wave's weight slice into registers (once) ----
    s16x8 wf[KC_N];                          // 192 VGPRs
    const unsigned short* wbase = Wpk + ((size_t)cgrp * KC_N * 64 + l) * 8;
    #pragma unroll
    for (int kc = 0; kc < KC_N; ++kc)
        wf[kc] = *reinterpret_cast<const s16x8*>(wbase + (size_t)kc * 64 * 8);

    // epilogue thread identity: (batch eb, hidden eu)
    const int eb = tid >> 4, eu = tid & 15;
    const int jh = bxc * 16 + eu;
    const float4 bias = *reinterpret_cast<const float4*>(bias_p + bxc * 64 + eu * 4);
    const size_t sidx = (size_t)(b0 + eb) * H_ + jh;
    float c_val = c0[jh];                    // c is thread-private across all steps

    int* slots = bar + bg * 64 * 16;         // this group's 64 padded slots

    for (int t = 0; t < T_; ++t) {
        const unsigned short* hin = (t & 1) ? h_b : h_a;
        unsigned short*      hout = (t & 1) ? h_a : h_b;

        // ---- prefetch mask (scalar, no cross-block dep; latency hides in spin)
        const int m = mask[(b0 + eb) * T_ + t];

        // ---- stage x_t (fp32 -> bf16); no cross-block dependency ----
        #pragma unroll
        for (int i = 0; i < 8; ++i) {
            int e = i * 256 + tid;           // 16 rows x 128 float4
            int r = e >> 7, c4 = e & 127;
            float4 v = *reinterpret_cast<const float4*>(
                x + ((size_t)(b0 + r) * T_ + t) * D_ + c4 * 4);
            unsigned int lo = ((unsigned int)f2bf(v.y) << 16) | f2bf(v.x);
            unsigned int hi = ((unsigned int)f2bf(v.w) << 16) | f2bf(v.z);
            *reinterpret_cast<uint2*>(&At[r * AP + c4 * 4]) = make_uint2(lo, hi);
        }

        // ---- wait: all 64 group blocks finished step t-1 ----
        if (t > 0) {
            if (tid < 64) {
                while (__hip_atomic_load(&slots[tid * 16], __ATOMIC_RELAXED,
                                         __HIP_MEMORY_SCOPE_AGENT) < t)
                    __builtin_amdgcn_s_sleep(1);
            }
            __syncthreads();
            __builtin_amdgcn_fence(__ATOMIC_ACQUIRE, "agent");  // inv L1/L2
        }

        // ---- stage h(t-1) ----
        #pragma unroll
        for (int i = 0; i < 8; ++i) {
            int e = i * 256 + tid;           // 16 rows x 128 chunks of 8 bf16
            int r = e >> 7, c8 = e & 127;
            uint4 v = *reinterpret_cast<const uint4*>(hin + (size_t)(b0 + r) * H_ + c8 * 8);
            *reinterpret_cast<uint4*>(&At[r * AP + D_ + c8 * 8]) = v;
        }
        __syncthreads();

        // ---- MFMA: 48 k-chunks, 4 independent acc chains ----
        f32x4 acc0 = {0.f,0.f,0.f,0.f}, acc1 = {0.f,0.f,0.f,0.f};
        f32x4 acc2 = {0.f,0.f,0.f,0.f}, acc3 = {0.f,0.f,0.f,0.f};
        const unsigned short* atp = &At[l15 * AP + quad * 8];
        #pragma unroll
        for (int kc = 0; kc < KC_N; kc += 4) {
            s16x8 a0 = *reinterpret_cast<const s16x8*>(atp + (kc + 0) * 32);
            s16x8 a1 = *reinterpret_cast<const s16x8*>(atp + (kc + 1) * 32);
            s16x8 a2 = *reinterpret_cast<const s16x8*>(atp + (kc + 2) * 32);
            s16x8 a3 = *reinterpret_cast<const s16x8*>(atp + (kc + 3) * 32);
            acc0 = __builtin_amdgcn_mfma_f32_16x16x32_bf16(a0, wf[kc + 0], acc0, 0, 0, 0);
            acc1 = __builtin_amdgcn_mfma_f32_16x16x32_bf16(a1, wf[kc + 1], acc1, 0, 0, 0);
            acc2 = __builtin_amdgcn_mfma_f32_16x16x32_bf16(a2, wf[kc + 2], acc2, 0, 0, 0);
            acc3 = __builtin_amdgcn_mfma_f32_16x16x32_bf16(a3, wf[kc + 3], acc3, 0, 0, 0);
        }
        f32x4 accs = (acc0 + acc1) + (acc2 + acc3);
        #pragma unroll
        for (int r = 0; r < 4; ++r)          // C/D: col=lane&15, row=quad*4+r
            Dl[quad * 4 + r][w * 16 + l15] = accs[r];
        __syncthreads();

        // ---- fused LSTM cell epilogue ----
        float gi = sigm  (Dl[eb][eu * 4 + 0] + bias.x);
        float gf = sigm  (Dl[eb][eu * 4 + 1] + bias.y);
        float gg = tanh_f(Dl[eb][eu * 4 + 2] + bias.z);
        float go = sigm  (Dl[eb][eu * 4 + 3] + bias.w);
        float h_old = bf2f(At[eb * AP + D_ + jh]);
        float c_new = gf * c_val + gi * gg;
        float h_new = go * tanh_f(c_new);
        float h2 = m ? h_new : h_old;
        c_val    = m ? c_new : c_val;
        hout[sidx] = f2bf(h2);
        out[((size_t)(b0 + eb) * T_ + t) * H_ + jh] = h2;

        // ---- arrive: release h writes device-wide, bump own slot ----
        __builtin_amdgcn_fence(__ATOMIC_RELEASE, "agent");  // wb L2 after stores
        __syncthreads();
        if (tid == 0)
            __hip_atomic_store(&slots[bxc * 16], t + 1, __ATOMIC_RELAXED,
                               __HIP_MEMORY_SCOPE_AGENT);
    }
}

extern "C" void kernel_launch(void* const* d_in, const int* in_sizes, int n_in,
                              void* d_out, int out_size, void* d_ws, size_t ws_size,
                              hipStream_t stream)
{
    const float* x    = (const float*)d_in[0];
    const int*   mask = (const int*)d_in[1];
    const float* W_ih = (const float*)d_in[2];
    const float* W_hh = (const float*)d_in[3];
    const float* b_ih = (const float*)d_in[4];
    const float* b_hh = (const float*)d_in[5];
    const float* h0   = (const float*)d_in[6];
    const float* c0   = (const float*)d_in[7];
    float* out = (float*)d_out;

    // ws layout (~12.9 MB)
    char* wsb = (char*)d_ws;
    unsigned short* Wpk    = (unsigned short*)(wsb);             // 12,582,912 B
    float*          bias_p = (float*)(wsb + 12582912);           //     16,384 B
    unsigned short* h_a    = (unsigned short*)(wsb + 12599296);  //    131,072 B
    unsigned short* h_b    = (unsigned short*)(wsb + 12730368);  //    131,072 B
    int*            bar    = (int*)(wsb + 12861440);             //     16,384 B

    // ws re-poisoned every call -> re-pack + re-init every call (~15 us)
    pack_w<<<24576, 256, 0, stream>>>(W_ih, W_hh, Wpk);
    init_state<<<256, 256, 0, stream>>>(h0, b_ih, b_hh, h_a, bias_p, bar);

    lstm_persist<<<dim3(256), dim3(256), 0, stream>>>(
        x, mask, Wpk, bias_p, c0, h_a, h_b, out, bar);
}

// Round 4
// 4787.414 us; speedup vs baseline: 2.8257x; 2.8257x over previous
//
#include <hip/hip_runtime.h>

#define B_   64
#define T_   512
#define D_   512
#define H_   1024
#define G4   4096      // 4*H
#define KTOT 1536      // D + H
#define KC_N 48        // KTOT / 32
#define AP   1544      // padded LDS A-row stride (1536 + 8 shorts)

typedef float f32x4 __attribute__((ext_vector_type(4)));
typedef short s16x8 __attribute__((ext_vector_type(8)));

__device__ __forceinline__ unsigned short f2bf(float f) {
    unsigned int u = __float_as_uint(f);
    u = (u + 0x7fffu + ((u >> 16) & 1u)) >> 16;   // RNE
    return (unsigned short)u;
}
__device__ __forceinline__ float bf2f(unsigned short h) {
    return __uint_as_float(((unsigned int)h) << 16);
}
__device__ __forceinline__ float sigm(float x) { return 1.f / (1.f + __expf(-x)); }
__device__ __forceinline__ float tanh_f(float x) { return 1.f - 2.f / (__expf(2.f * x) + 1.f); }

// Pack [W_ih | W_hh] into exact MFMA B-fragment order, bf16, gate-interleaved
// packed col n = 4*j_hidden + gate. Wpk[(((c*48 + kc)*64 + lane))*8 + j] =
// W[row(n)][k], n = c*16 + (lane&15), k = kc*32 + (lane>>4)*8 + j.
__global__ __launch_bounds__(256) void pack_w(const float* __restrict__ W_ih,
                                              const float* __restrict__ W_hh,
                                              unsigned short* __restrict__ Wpk) {
    int tid = blockIdx.x * 256 + threadIdx.x;        // [0, 256*48*64*8)
    int j    = tid & 7;
    int lane = (tid >> 3) & 63;
    int rest = tid >> 9;
    int kc = rest % KC_N;
    int c  = rest / KC_N;
    int npk = c * 16 + (lane & 15);
    int jh = npk >> 2, g = npk & 3;
    int row = g * H_ + jh;                           // torch gate order i,f,g,o
    int k = kc * 32 + (lane >> 4) * 8 + j;
    float v = (k < D_) ? W_ih[row * D_ + k] : W_hh[row * H_ + (k - D_)];
    Wpk[tid] = f2bf(v);
}

__global__ __launch_bounds__(256) void init_state(const float* __restrict__ h0,
                                                  const float* __restrict__ b_ih,
                                                  const float* __restrict__ b_hh,
                                                  unsigned short* __restrict__ h_a,
                                                  float* __restrict__ bias_p,
                                                  int* __restrict__ bar) {
    int tid = blockIdx.x * 256 + threadIdx.x;        // 65536
    int j = tid & (H_ - 1);
    h_a[tid] = f2bf(h0[j]);
    if (tid < G4) {                                  // bias in packed-col order
        int jh = tid >> 2, g = tid & 3;
        bias_p[tid] = b_ih[g * H_ + jh] + b_hh[g * H_ + jh];
    }
    if (tid < 1024) bar[tid] = 0;                    // flags (contiguous dwords)
}

// Persistent recurrence: 256 blocks = 4 batch groups x 64 col blocks, all 512
// timesteps in one plain launch (grid == #CUs -> co-resident at 1 block/CU).
// Weights live in registers (48 s16x8 frags/lane). Cross-block h exchange and
// flags use relaxed AGENT-scope atomics only (single sc1 coherent ops at the
// MALL) -- NO release/acquire fences, so no buffer_wbl2 / buffer_inv.
__global__ __launch_bounds__(256, 1) void lstm_persist(
    const float* __restrict__ x, const int* __restrict__ mask,
    const unsigned short* __restrict__ Wpk, const float* __restrict__ bias_p,
    const float* __restrict__ c0,
    unsigned short* __restrict__ h_a, unsigned short* __restrict__ h_b,
    float* __restrict__ out, int* __restrict__ bar)
{
    __shared__ __align__(16) unsigned short At[16 * AP];  // [x_t | h] tile, bf16
    __shared__ float Dl[16][66];                          // gates f32, padded

    const int tid = threadIdx.x;
    const int blk = blockIdx.x;
    const int bg  = blk & 3;                 // batch group 0..3
    const int bxc = blk >> 2;                // col block 0..63
    const int b0  = bg * 16;
    const int w = tid >> 6, l = tid & 63;
    const int quad = l >> 4, l15 = l & 15;
    const int cgrp = bxc * 4 + w;            // global 16-col group [0,256)

    // ---- load this wave's weight slice into registers (once) ----
    s16x8 wf[KC_N];                          // 192 regs (unified VGPR/AGPR file)
    const unsigned short* wbase = Wpk + ((size_t)cgrp * KC_N * 64 + l) * 8;
    #pragma unroll
    for (int kc = 0; kc < KC_N; ++kc)
        wf[kc] = *reinterpret_cast<const s16x8*>(wbase + (size_t)kc * 64 * 8);

    // epilogue thread identity: (batch eb, hidden eu)
    const int eb = tid >> 4, eu = tid & 15;
    const int jh = bxc * 16 + eu;
    const float4 bias = *reinterpret_cast<const float4*>(bias_p + bxc * 64 + eu * 4);
    const size_t sidx = (size_t)(b0 + eb) * H_ + jh;
    float c_val = c0[jh];                    // c is thread-private across all steps

    int* flags = bar + bg * 64;              // this group's 64 contiguous flags

    for (int t = 0; t < T_; ++t) {
        const unsigned short* hin = (t & 1) ? h_b : h_a;
        unsigned short*      hout = (t & 1) ? h_a : h_b;

        // ---- prefetch mask (latency hides in the spin) ----
        const int m = mask[(b0 + eb) * T_ + t];

        // ---- stage x_t (fp32 -> bf16); no cross-block dependency ----
        #pragma unroll
        for (int i = 0; i < 8; ++i) {
            int e = i * 256 + tid;           // 16 rows x 128 float4
            int r = e >> 7, c4 = e & 127;
            float4 v = *reinterpret_cast<const float4*>(
                x + ((size_t)(b0 + r) * T_ + t) * D_ + c4 * 4);
            unsigned int lo = ((unsigned int)f2bf(v.y) << 16) | f2bf(v.x);
            unsigned int hi = ((unsigned int)f2bf(v.w) << 16) | f2bf(v.z);
            *reinterpret_cast<uint2*>(&At[r * AP + c4 * 4]) = make_uint2(lo, hi);
        }

        // ---- wait: all 64 group blocks finished step t-1 (coalesced poll) ----
        if (t > 0) {
            if (tid < 64) {
                while (__hip_atomic_load(&flags[tid], __ATOMIC_RELAXED,
                                         __HIP_MEMORY_SCOPE_AGENT) < t)
                    __builtin_amdgcn_s_sleep(2);
            }
            __syncthreads();
        }

        // ---- stage h(t-1) via coherence-point loads (no fence needed) ----
        const unsigned long long* hq = reinterpret_cast<const unsigned long long*>(hin);
        #pragma unroll
        for (int i = 0; i < 16; ++i) {
            int e = i * 256 + tid;           // qword idx: 16 rows x 256 q/row
            int r = e >> 8, c4 = e & 255;
            unsigned long long v = __hip_atomic_load(
                &hq[(size_t)(b0 + r) * (H_ / 4) + c4],
                __ATOMIC_RELAXED, __HIP_MEMORY_SCOPE_AGENT);
            *reinterpret_cast<unsigned long long*>(&At[r * AP + D_ + c4 * 4]) = v;
        }
        __syncthreads();

        // ---- MFMA: 48 k-chunks, 4 independent acc chains ----
        f32x4 acc0 = {0.f,0.f,0.f,0.f}, acc1 = {0.f,0.f,0.f,0.f};
        f32x4 acc2 = {0.f,0.f,0.f,0.f}, acc3 = {0.f,0.f,0.f,0.f};
        const unsigned short* atp = &At[l15 * AP + quad * 8];
        #pragma unroll
        for (int kc = 0; kc < KC_N; kc += 4) {
            s16x8 a0 = *reinterpret_cast<const s16x8*>(atp + (kc + 0) * 32);
            s16x8 a1 = *reinterpret_cast<const s16x8*>(atp + (kc + 1) * 32);
            s16x8 a2 = *reinterpret_cast<const s16x8*>(atp + (kc + 2) * 32);
            s16x8 a3 = *reinterpret_cast<const s16x8*>(atp + (kc + 3) * 32);
            acc0 = __builtin_amdgcn_mfma_f32_16x16x32_bf16(a0, wf[kc + 0], acc0, 0, 0, 0);
            acc1 = __builtin_amdgcn_mfma_f32_16x16x32_bf16(a1, wf[kc + 1], acc1, 0, 0, 0);
            acc2 = __builtin_amdgcn_mfma_f32_16x16x32_bf16(a2, wf[kc + 2], acc2, 0, 0, 0);
            acc3 = __builtin_amdgcn_mfma_f32_16x16x32_bf16(a3, wf[kc + 3], acc3, 0, 0, 0);
        }
        f32x4 accs = (acc0 + acc1) + (acc2 + acc3);
        #pragma unroll
        for (int r = 0; r < 4; ++r)          // C/D: col=lane&15, row=quad*4+r
            Dl[quad * 4 + r][w * 16 + l15] = accs[r];
        __syncthreads();

        // ---- fused LSTM cell epilogue ----
        float gi = sigm  (Dl[eb][eu * 4 + 0] + bias.x);
        float gf = sigm  (Dl[eb][eu * 4 + 1] + bias.y);
        float gg = tanh_f(Dl[eb][eu * 4 + 2] + bias.z);
        float go = sigm  (Dl[eb][eu * 4 + 3] + bias.w);
        float h_old = bf2f(At[eb * AP + D_ + jh]);
        float c_new = gf * c_val + gi * gg;
        float h_new = go * tanh_f(c_new);
        float h2 = m ? h_new : h_old;
        c_val    = m ? c_new : c_val;
        out[((size_t)(b0 + eb) * T_ + t) * H_ + jh] = h2;

        // ---- publish h: pair bf16 via shfl, even lanes store one dword ----
        unsigned short hu = f2bf(h2);
        unsigned int partner = (unsigned int)(unsigned short)__shfl_xor((int)hu, 1);
        unsigned int hv = (unsigned int)hu | (partner << 16);
        if ((tid & 1) == 0)
            __hip_atomic_store(reinterpret_cast<unsigned int*>(hout) + (sidx >> 1),
                               hv, __ATOMIC_RELAXED, __HIP_MEMORY_SCOPE_AGENT);

        // ---- arrive: syncthreads drains vmcnt(0); then bump own flag ----
        __syncthreads();
        if (tid == 0)
            __hip_atomic_store(&flags[bxc], t + 1, __ATOMIC_RELAXED,
                               __HIP_MEMORY_SCOPE_AGENT);
    }
}

extern "C" void kernel_launch(void* const* d_in, const int* in_sizes, int n_in,
                              void* d_out, int out_size, void* d_ws, size_t ws_size,
                              hipStream_t stream)
{
    const float* x    = (const float*)d_in[0];
    const int*   mask = (const int*)d_in[1];
    const float* W_ih = (const float*)d_in[2];
    const float* W_hh = (const float*)d_in[3];
    const float* b_ih = (const float*)d_in[4];
    const float* b_hh = (const float*)d_in[5];
    const float* h0   = (const float*)d_in[6];
    const float* c0   = (const float*)d_in[7];
    float* out = (float*)d_out;

    // ws layout (~12.9 MB)
    char* wsb = (char*)d_ws;
    unsigned short* Wpk    = (unsigned short*)(wsb);             // 12,582,912 B
    float*          bias_p = (float*)(wsb + 12582912);           //     16,384 B
    unsigned short* h_a    = (unsigned short*)(wsb + 12599296);  //    131,072 B
    unsigned short* h_b    = (unsigned short*)(wsb + 12730368);  //    131,072 B
    int*            bar    = (int*)(wsb + 12861440);             //      4,096 B

    // ws re-poisoned every call -> re-pack + re-init every call (~15 us)
    pack_w<<<24576, 256, 0, stream>>>(W_ih, W_hh, Wpk);
    init_state<<<256, 256, 0, stream>>>(h0, b_ih, b_hh, h_a, bias_p, bar);

    lstm_persist<<<dim3(256), dim3(256), 0, stream>>>(
        x, mask, Wpk, bias_p, c0, h_a, h_b, out, bar);
}